// Round 1
// baseline (642.288 us; speedup 1.0000x reference)
//
#include <hip/hip_runtime.h>
#include <cmath>

typedef __bf16 bf16_t;
typedef bf16_t bf16x8 __attribute__((ext_vector_type(8)));
typedef bf16_t bf16x4 __attribute__((ext_vector_type(4)));
typedef float floatx4 __attribute__((ext_vector_type(4)));

#define EPS_ 1e-5f
#define QSCALE 0.17677669529663689f
#define NWIN 49

// ---------- async global->LDS (16B per lane) ----------
__device__ __forceinline__ void gload16(const bf16_t* g, bf16_t* l) {
  __builtin_amdgcn_global_load_lds(
      (const __attribute__((address_space(1))) void*)g,
      (__attribute__((address_space(3))) void*)l, 16, 0, 0);
}

// ---------- fp32 -> bf16 weight conversion ----------
__global__ void cvt_bf16(const float* __restrict__ s, bf16_t* __restrict__ d, int n4) {
  int i = blockIdx.x * 256 + threadIdx.x;
  if (i < n4) {
    float4 v = ((const float4*)s)[i];
    bf16x4 o;
    o[0] = (bf16_t)v.x; o[1] = (bf16_t)v.y; o[2] = (bf16_t)v.z; o[3] = (bf16_t)v.w;
    ((bf16x4*)d)[i] = o;
  }
}

// ---------- LN1 stats over C for NCHW input ----------
__global__ __launch_bounds__(256)
void ln_stats_nchw(const float* __restrict__ x, float* __restrict__ mu, float* __restrict__ rs) {
  const int tl = threadIdx.x & 63;
  const int wv = threadIdx.x >> 6;
  const int t = blockIdx.x * 64 + tl;       // token = b*196 + p
  const int b = t / 196;
  const int p = t - b * 196;
  const float* xp = x + (long)b * 100352 + p;
  float s = 0.f, ss = 0.f;
  const int cbeg = wv * 128;
  for (int c = cbeg; c < cbeg + 128; ++c) {
    const float v = xp[(long)c * 196];
    s += v; ss += v * v;
  }
  __shared__ float sb[4][64], qb[4][64];
  sb[wv][tl] = s; qb[wv][tl] = ss;
  __syncthreads();
  if (wv == 0) {
    s  = sb[0][tl] + sb[1][tl] + sb[2][tl] + sb[3][tl];
    ss = qb[0][tl] + qb[1][tl] + qb[2][tl] + qb[3][tl];
    const float m = s * (1.f / 512.f);
    const float var = ss * (1.f / 512.f) - m * m;
    mu[t] = m;
    rs[t] = rsqrtf(var + EPS_);
  }
}

// ---------- LN1 apply + NCHW->token-major transpose; writes XT (raw x, f32) and A (normalized, bf16) ----------
__global__ __launch_bounds__(256)
void ln1_apply(const float* __restrict__ x, const float* __restrict__ mu, const float* __restrict__ rs,
               const float* __restrict__ w, const float* __restrict__ bb,
               float* __restrict__ XT, bf16_t* __restrict__ A) {
  __shared__ float tile[64][53];            // 53: gcd(53,32)=1 -> conflict-free
  const int bid = blockIdx.x;
  const int ct = bid & 7;
  const int pt = (bid >> 3) & 3;
  const int b = bid >> 5;
  const int p0 = pt * 49, c0 = ct * 64;
  const long xbase = (long)b * 100352;
  for (int idx = threadIdx.x; idx < 3136; idx += 256) {
    const int cl = idx / 49;
    const int pl = idx - cl * 49;
    tile[cl][pl] = x[xbase + (long)(c0 + cl) * 196 + p0 + pl];
  }
  __syncthreads();
  const int tbase = b * 196 + p0;
  for (int idx = threadIdx.x; idx < 3136; idx += 256) {
    const int pl = idx >> 6;
    const int cl = idx & 63;
    const int t = tbase + pl;
    const float v = tile[cl][pl];
    const long o = (long)t * 512 + c0 + cl;
    XT[o] = v;
    A[o] = (bf16_t)((v - mu[t]) * rs[t] * w[c0 + cl] + bb[c0 + cl]);
  }
}

// ---------- LN2 stats (token-major f32 rows) ----------
__global__ __launch_bounds__(256)
void ln_stats_row(const float* __restrict__ X, float* __restrict__ mu, float* __restrict__ rs) {
  const int wv = threadIdx.x >> 6;
  const int lane = threadIdx.x & 63;
  const long t = (long)blockIdx.x * 4 + wv;
  const float* row = X + t * 512;
  const float4 a = *(const float4*)(row + lane * 8);
  const float4 c = *(const float4*)(row + lane * 8 + 4);
  float s  = a.x + a.y + a.z + a.w + c.x + c.y + c.z + c.w;
  float ss = a.x*a.x + a.y*a.y + a.z*a.z + a.w*a.w + c.x*c.x + c.y*c.y + c.z*c.z + c.w*c.w;
  #pragma unroll
  for (int m_ = 32; m_ > 0; m_ >>= 1) { s += __shfl_xor(s, m_); ss += __shfl_xor(ss, m_); }
  if (lane == 0) {
    const float m = s * (1.f / 512.f);
    const float var = ss * (1.f / 512.f) - m * m;
    mu[t] = m; rs[t] = rsqrtf(var + EPS_);
  }
}

// ---------- LN2 apply -> bf16 tokens ----------
__global__ __launch_bounds__(256)
void ln2_apply(const float* __restrict__ X, const float* __restrict__ mu,
               const float* __restrict__ rs, const float* __restrict__ w,
               const float* __restrict__ bb, bf16_t* __restrict__ Z) {
  const long i = ((long)blockIdx.x * 256 + threadIdx.x) * 4;
  const int t = (int)(i >> 9);
  const int c = (int)(i & 511);
  const float m = mu[t], r = rs[t];
  const float4 v = *(const float4*)(X + i);
  bf16x4 o;
  o[0] = (bf16_t)((v.x - m) * r * w[c + 0] + bb[c + 0]);
  o[1] = (bf16_t)((v.y - m) * r * w[c + 1] + bb[c + 1]);
  o[2] = (bf16_t)((v.z - m) * r * w[c + 2] + bb[c + 2]);
  o[3] = (bf16_t)((v.w - m) * r * w[c + 3] + bb[c + 3]);
  *(bf16x4*)(Z + i) = o;
}

// ---------- bf16 MFMA GEMM, A (M,K) row-major, B (N,K) row-major (i.e. B^T math), 128x128 tile, BK=32 ----------
// EPI 0: qkv   out_bf16[row*1536+col] = (acc+bias[col]) * (col<512 ? qscale : 1)
// EPI 1: proj  out_f32 = res + gamma[col]*(acc+bias[col])      (X1 = x + g1*proj)
// EPI 2: fc1   out_bf16 = gelu_exact(acc+bias[col])
// EPI 3: fc2   out_f32 = res + gamma[col]*(acc+bias[col])      (final token-major, in-place over X1)
template<int EPI>
__global__ __launch_bounds__(256)
void gemm_bt(const bf16_t* __restrict__ A, const bf16_t* __restrict__ Bw,
             const float* __restrict__ bias, const float* __restrict__ res,
             const float* __restrict__ gamma,
             bf16_t* __restrict__ outb, float* __restrict__ outf,
             const int K, const int N) {
  __shared__ bf16_t As[4096];
  __shared__ bf16_t Bs[4096];
  const int tid = threadIdx.x;
  const int wave = tid >> 6;
  const int lane = tid & 63;
  const long m0 = (long)blockIdx.x * 128;
  const long n0 = (long)blockIdx.y * 128;
  const int srow = tid >> 2;
  const int skk = (tid & 3) << 3;
  const bf16_t* ag = A + (m0 + srow) * K + skk;
  const bf16_t* bg = Bw + (n0 + srow) * K + skk;
  bf16_t* la0 = As + tid * 8;
  bf16_t* la1 = As + 2048 + tid * 8;
  bf16_t* lb0 = Bs + tid * 8;
  bf16_t* lb1 = Bs + 2048 + tid * 8;
  const int wm = (wave >> 1) << 6;
  const int wn = (wave & 1) << 6;
  const int lm = lane & 15;
  const int lk = (lane >> 4) << 3;
  floatx4 acc[4][4] = {};
  const int nk = K >> 5;
  const int astride = K << 6;  // 64*K
  for (int kt = 0; kt < nk; ++kt) {
    gload16(ag, la0);
    gload16(ag + astride, la1);
    gload16(bg, lb0);
    gload16(bg + astride, lb1);
    __syncthreads();
    bf16x8 af[4], bfr[4];
    #pragma unroll
    for (int i = 0; i < 4; ++i)
      af[i] = *(const bf16x8*)(As + (wm + i * 16 + lm) * 32 + lk);
    #pragma unroll
    for (int j = 0; j < 4; ++j)
      bfr[j] = *(const bf16x8*)(Bs + (wn + j * 16 + lm) * 32 + lk);
    #pragma unroll
    for (int i = 0; i < 4; ++i)
      #pragma unroll
      for (int j = 0; j < 4; ++j)
        acc[i][j] = __builtin_amdgcn_mfma_f32_16x16x32_bf16(af[i], bfr[j], acc[i][j], 0, 0, 0);
    __syncthreads();
    ag += 32; bg += 32;
  }
  const int r0 = (lane >> 4) << 2;
  const int cl = lane & 15;
  #pragma unroll
  for (int j = 0; j < 4; ++j) {
    const int colg = (int)n0 + wn + j * 16 + cl;
    const float bcol = bias[colg];
    float gcol = 0.f;
    if (EPI == 1 || EPI == 3) gcol = gamma[colg];
    #pragma unroll
    for (int i = 0; i < 4; ++i) {
      #pragma unroll
      for (int r = 0; r < 4; ++r) {
        const long rowg = m0 + wm + i * 16 + r0 + r;
        float v = acc[i][j][r];
        if (EPI == 0) {
          v += bcol;
          if (colg < 512) v *= QSCALE;
          outb[rowg * 1536 + colg] = (bf16_t)v;
        } else if (EPI == 2) {
          v += bcol;
          v = 0.5f * v * (1.f + erff(v * 0.70710678118654752f));
          outb[rowg * (long)N + colg] = (bf16_t)v;
        } else {
          const long o = rowg * (long)N + colg;
          outf[o] = res[o] + gcol * (v + bcol);
        }
      }
    }
  }
}

// ---------- windowed attention: one wave per (window, head); lane = query row ----------
__global__ __launch_bounds__(256)
void attn_kern(const bf16_t* __restrict__ QKV, const float* __restrict__ rel_bias,
               bf16_t* __restrict__ AT) {
  __shared__ float kvs[4][2][NWIN * 32];   // per-wave K and V, 50176 B total
  const int wave = threadIdx.x >> 6;
  const int lane = threadIdx.x & 63;
  const int gw = blockIdx.x * 4 + wave;    // [0, 8192)
  const int wd = gw >> 4;                  // window id [0, 512)
  const int head = gw & 15;
  const int b = wd >> 2;
  const int wi = (wd >> 1) & 1;
  const int wj = wd & 1;
  float* ks = kvs[wave][0];
  float* vs = kvs[wave][1];
  const long qkvbase = (long)b * 196 * 1536;
  // stage K,V (shift map folded into addressing)
  for (int idx8 = lane; idx8 < 196; idx8 += 64) {
    const int n = idx8 >> 2;
    const int d0 = (idx8 & 3) << 3;
    const int ti_ = n / 7, tj_ = n - ti_ * 7;
    int h = wi * 7 + ti_ + 3; if (h >= 14) h -= 14;
    int w = wj * 7 + tj_ + 3; if (w >= 14) w -= 14;
    const bf16_t* kp = QKV + qkvbase + (long)(h * 14 + w) * 1536 + 512 + head * 32 + d0;
    const bf16x8 kk = *(const bf16x8*)kp;
    const bf16x8 vv = *(const bf16x8*)(kp + 512);
    float* kd = ks + n * 32 + d0;
    float* vd = vs + n * 32 + d0;
    #pragma unroll
    for (int e = 0; e < 8; ++e) { kd[e] = (float)kk[e]; vd[e] = (float)vv[e]; }
  }
  // per-lane q (lanes >=49 clamp to 48, never store)
  const int li = lane < 49 ? lane : 48;
  const int ti = li / 7, tj = li - (li / 7) * 7;
  int h = wi * 7 + ti + 3; if (h >= 14) h -= 14;
  int w = wj * 7 + tj + 3; if (w >= 14) w -= 14;
  const long t_i = (long)b * 196 + h * 14 + w;
  float q[32];
  {
    const bf16_t* qp = QKV + t_i * 1536 + head * 32;   // q pre-scaled in qkv epilogue
    #pragma unroll
    for (int d8 = 0; d8 < 4; ++d8) {
      const bf16x8 qq = *(const bf16x8*)(qp + d8 * 8);
      #pragma unroll
      for (int e = 0; e < 8; ++e) q[d8 * 8 + e] = (float)qq[e];
    }
  }
  const int hh = wi * 7 + ti, ww = wj * 7 + tj;        // unshifted coords for mask regions
  const int ri = (hh < 7 ? 0 : (hh < 11 ? 1 : 2)) * 3 + (ww < 7 ? 0 : (ww < 11 ? 1 : 2));
  __syncthreads();
  // pass 1: scores + bias + mask
  float s[NWIN];
  float mx = -1e30f;
  #pragma unroll
  for (int j = 0; j < NWIN; ++j) {
    const float* kr = ks + j * 32;
    float a = 0.f;
    #pragma unroll
    for (int dd = 0; dd < 32; dd += 4) {
      const float4 kk = *(const float4*)(kr + dd);
      a += q[dd] * kk.x + q[dd + 1] * kk.y + q[dd + 2] * kk.z + q[dd + 3] * kk.w;
    }
    const int sjt = j / 7, sjc = j - sjt * 7;
    const int bidx = (ti - sjt + 6) * 13 + (tj - sjc + 6);
    const float bias = rel_bias[bidx * 16 + head];
    const int h2 = wi * 7 + sjt, w2 = wj * 7 + sjc;
    const int rj = (h2 < 7 ? 0 : (h2 < 11 ? 1 : 2)) * 3 + (w2 < 7 ? 0 : (w2 < 11 ? 1 : 2));
    const float sv = a + bias + ((ri != rj) ? -100.f : 0.f);
    s[j] = sv;
    mx = fmaxf(mx, sv);
  }
  float sum = 0.f;
  #pragma unroll
  for (int j = 0; j < NWIN; ++j) { const float e = __expf(s[j] - mx); s[j] = e; sum += e; }
  const float inv = 1.f / sum;
  // pass 2: P @ V
  float oacc[32] = {};
  #pragma unroll
  for (int j = 0; j < NWIN; ++j) {
    const float p = s[j];
    const float* vr = vs + j * 32;
    #pragma unroll
    for (int dd = 0; dd < 32; dd += 4) {
      const float4 vv = *(const float4*)(vr + dd);
      oacc[dd] += p * vv.x; oacc[dd + 1] += p * vv.y;
      oacc[dd + 2] += p * vv.z; oacc[dd + 3] += p * vv.w;
    }
  }
  if (lane < 49) {
    bf16_t* op = AT + t_i * 512 + head * 32;
    #pragma unroll
    for (int d8 = 0; d8 < 4; ++d8) {
      bf16x8 ov;
      #pragma unroll
      for (int e = 0; e < 8; ++e) ov[e] = (bf16_t)(oacc[d8 * 8 + e] * inv);
      *(bf16x8*)(op + d8 * 8) = ov;
    }
  }
}

// ---------- final token-major f32 -> NCHW ----------
__global__ __launch_bounds__(256)
void out_transpose(const float* __restrict__ F, float* __restrict__ out) {
  __shared__ float tile[49][65];
  const int bid = blockIdx.x;
  const int ct = bid & 7;
  const int pt = (bid >> 3) & 3;
  const int b = bid >> 5;
  const int p0 = pt * 49, c0 = ct * 64;
  const int tbase = b * 196 + p0;
  for (int idx = threadIdx.x; idx < 3136; idx += 256) {
    const int pl = idx >> 6;
    const int cl = idx & 63;
    tile[pl][cl] = F[(long)(tbase + pl) * 512 + c0 + cl];
  }
  __syncthreads();
  const long obase = (long)b * 100352;
  for (int idx = threadIdx.x; idx < 3136; idx += 256) {
    const int cl = idx / 49;
    const int pl = idx - cl * 49;
    out[obase + (long)(c0 + cl) * 196 + p0 + pl] = tile[pl][cl];
  }
}

extern "C" void kernel_launch(void* const* d_in, const int* in_sizes, int n_in,
                              void* d_out, int out_size, void* d_ws, size_t ws_size,
                              hipStream_t stream) {
  const float* x      = (const float*)d_in[0];
  const float* ln1_w  = (const float*)d_in[1];
  const float* ln1_b  = (const float*)d_in[2];
  const float* qkv_w  = (const float*)d_in[3];
  const float* qkv_b  = (const float*)d_in[4];
  const float* relb   = (const float*)d_in[5];
  const float* proj_w = (const float*)d_in[6];
  const float* proj_b = (const float*)d_in[7];
  const float* gamma1 = (const float*)d_in[8];
  const float* ln2_w  = (const float*)d_in[9];
  const float* ln2_b  = (const float*)d_in[10];
  const float* fc1_w  = (const float*)d_in[11];
  const float* fc1_b  = (const float*)d_in[12];
  const float* fc2_w  = (const float*)d_in[13];
  const float* fc2_b  = (const float*)d_in[14];
  const float* gamma2 = (const float*)d_in[15];
  float* out = (float*)d_out;
  char* ws = (char*)d_ws;

  float*  mu1 = (float*)(ws + 0);
  float*  rs1 = (float*)(ws + 100352);
  float*  mu2 = (float*)(ws + 200704);
  float*  rs2 = (float*)(ws + 301056);
  bf16_t* Wq  = (bf16_t*)(ws + 401408);
  bf16_t* Wp  = (bf16_t*)(ws + 1974272);
  bf16_t* W1  = (bf16_t*)(ws + 2498560);
  bf16_t* W2  = (bf16_t*)(ws + 4595712);
  bf16_t* A   = (bf16_t*)(ws + 6692864);    // LN1 tokens; later reused as LN2 tokens
  float*  XT  = (float*) (ws + 32382976);   // raw x, token-major
  float*  X1  = (float*) (ws + 83763200);   // x + g1*attn branch; later final token-major
  bf16_t* QKV = (bf16_t*)(ws + 135143424);
  bf16_t* AT  = (bf16_t*)(ws + 212213760);
  bf16_t* Hb  = (bf16_t*)(ws + 135143424);  // gelu(fc1) overlaps dead QKV+AT (102,760,448 B)

  // weights -> bf16
  cvt_bf16<<<768,  256, 0, stream>>>(qkv_w, Wq, 196608);
  cvt_bf16<<<256,  256, 0, stream>>>(proj_w, Wp, 65536);
  cvt_bf16<<<1024, 256, 0, stream>>>(fc1_w, W1, 262144);
  cvt_bf16<<<1024, 256, 0, stream>>>(fc2_w, W2, 262144);

  // LN1 + transpose to token-major
  ln_stats_nchw<<<392, 256, 0, stream>>>(x, mu1, rs1);
  ln1_apply<<<4096, 256, 0, stream>>>(x, mu1, rs1, ln1_w, ln1_b, XT, A);

  // qkv GEMM (q pre-scaled)
  gemm_bt<0><<<dim3(196, 12), 256, 0, stream>>>(A, Wq, qkv_b, nullptr, nullptr, QKV, nullptr, 512, 1536);

  // shifted-window attention
  attn_kern<<<2048, 256, 0, stream>>>(QKV, relb, AT);

  // proj GEMM, fused X1 = x + g1*(out+b)
  gemm_bt<1><<<dim3(196, 4), 256, 0, stream>>>(AT, Wp, proj_b, XT, gamma1, nullptr, X1, 512, 512);

  // LN2
  ln_stats_row<<<6272, 256, 0, stream>>>(X1, mu2, rs2);
  ln2_apply<<<12544, 256, 0, stream>>>(X1, mu2, rs2, ln2_w, ln2_b, A);

  // MLP
  gemm_bt<2><<<dim3(196, 16), 256, 0, stream>>>(A, W1, fc1_b, nullptr, nullptr, Hb, nullptr, 512, 2048);
  gemm_bt<3><<<dim3(196, 4), 256, 0, stream>>>(Hb, W2, fc2_b, X1, gamma2, nullptr, X1, 2048, 512);

  // token-major -> NCHW
  out_transpose<<<4096, 256, 0, stream>>>(X1, out);
}

// Round 3
// 580.952 us; speedup vs baseline: 1.1056x; 1.1056x over previous
//
#include <hip/hip_runtime.h>
#include <cmath>
#include <cstdint>

typedef float floatx4 __attribute__((ext_vector_type(4)));
typedef float floatx2 __attribute__((ext_vector_type(2)));

#define EPS_ 1e-5f
#define QSCALE 0.17677669529663689f
#define NWIN 49

// ---------- async global->LDS (16B per lane) ----------
__device__ __forceinline__ void gload16(const uint8_t* g, uint8_t* l) {
  __builtin_amdgcn_global_load_lds(
      (const __attribute__((address_space(1))) void*)g,
      (__attribute__((address_space(3))) void*)l, 16, 0, 0);
}

// ---------- fp8 e4m3 pack/unpack (word-select must be an immediate) ----------
template<bool HI>
__device__ __forceinline__ int pk_fp8(float a, float b, int old) {
  return __builtin_amdgcn_cvt_pk_fp8_f32(a, b, old, HI);
}
__device__ __forceinline__ int pk_fp8x4(float v0, float v1, float v2, float v3) {
  int w = pk_fp8<false>(v0, v1, 0);
  return pk_fp8<true>(v2, v3, w);
}
__device__ __forceinline__ void up_fp8x4(unsigned int d, float* o) {
  floatx2 lo = __builtin_amdgcn_cvt_pk_f32_fp8(d, false);
  floatx2 hi = __builtin_amdgcn_cvt_pk_f32_fp8(d, true);
  o[0] = lo[0]; o[1] = lo[1]; o[2] = hi[0]; o[3] = hi[1];
}

// ---------- fp32 -> fp8 weight conversion (4 floats -> 1 dword) ----------
__global__ void cvt_fp8(const float* __restrict__ s, uint8_t* __restrict__ d, int n4) {
  int i = blockIdx.x * 256 + threadIdx.x;
  if (i < n4) {
    float4 v = ((const float4*)s)[i];
    ((int*)d)[i] = pk_fp8x4(v.x, v.y, v.z, v.w);
  }
}

// ---------- LN1 stats over C for NCHW input ----------
__global__ __launch_bounds__(256)
void ln_stats_nchw(const float* __restrict__ x, float* __restrict__ mu, float* __restrict__ rs) {
  const int tl = threadIdx.x & 63;
  const int wv = threadIdx.x >> 6;
  const int t = blockIdx.x * 64 + tl;       // token = b*196 + p
  const int b = t / 196;
  const int p = t - b * 196;
  const float* xp = x + (long)b * 100352 + p;
  float s = 0.f, ss = 0.f;
  const int cbeg = wv * 128;
  for (int c = cbeg; c < cbeg + 128; ++c) {
    const float v = xp[(long)c * 196];
    s += v; ss += v * v;
  }
  __shared__ float sb[4][64], qb[4][64];
  sb[wv][tl] = s; qb[wv][tl] = ss;
  __syncthreads();
  if (wv == 0) {
    s  = sb[0][tl] + sb[1][tl] + sb[2][tl] + sb[3][tl];
    ss = qb[0][tl] + qb[1][tl] + qb[2][tl] + qb[3][tl];
    const float m = s * (1.f / 512.f);
    const float var = ss * (1.f / 512.f) - m * m;
    mu[t] = m;
    rs[t] = rsqrtf(var + EPS_);
  }
}

// ---------- LN1 apply + NCHW->token-major transpose; writes XT (raw x, f32) and A (normalized, fp8) ----------
__global__ __launch_bounds__(256)
void ln1_apply(const float* __restrict__ x, const float* __restrict__ mu, const float* __restrict__ rs,
               const float* __restrict__ w, const float* __restrict__ bb,
               float* __restrict__ XT, uint8_t* __restrict__ A) {
  __shared__ float tile[64][53];            // 53: gcd(53,32)=1 -> conflict-free
  const int bid = blockIdx.x;
  const int ct = bid & 7;
  const int pt = (bid >> 3) & 3;
  const int b = bid >> 5;
  const int p0 = pt * 49, c0 = ct * 64;
  const long xbase = (long)b * 100352;
  for (int idx = threadIdx.x; idx < 3136; idx += 256) {
    const int cl = idx / 49;
    const int pl = idx - cl * 49;
    tile[cl][pl] = x[xbase + (long)(c0 + cl) * 196 + p0 + pl];
  }
  __syncthreads();
  const int tbase = b * 196 + p0;
  for (int idx = threadIdx.x; idx < 3136; idx += 256) {
    const int pl = idx >> 6;
    const int cl = idx & 63;
    const int t = tbase + pl;
    XT[(long)t * 512 + c0 + cl] = tile[cl][pl];
  }
  for (int idx = threadIdx.x; idx < 784; idx += 256) {
    const int pl = idx >> 4;                // 0..48
    const int cq = (idx & 15) << 2;         // 0..60 step 4
    const int t = tbase + pl;
    const float m = mu[t], rr = rs[t];
    float v0 = (tile[cq + 0][pl] - m) * rr * w[c0 + cq + 0] + bb[c0 + cq + 0];
    float v1 = (tile[cq + 1][pl] - m) * rr * w[c0 + cq + 1] + bb[c0 + cq + 1];
    float v2 = (tile[cq + 2][pl] - m) * rr * w[c0 + cq + 2] + bb[c0 + cq + 2];
    float v3 = (tile[cq + 3][pl] - m) * rr * w[c0 + cq + 3] + bb[c0 + cq + 3];
    *(int*)(A + (long)t * 512 + c0 + cq) = pk_fp8x4(v0, v1, v2, v3);
  }
}

// ---------- LN2 stats (token-major f32 rows) ----------
__global__ __launch_bounds__(256)
void ln_stats_row(const float* __restrict__ X, float* __restrict__ mu, float* __restrict__ rs) {
  const int wv = threadIdx.x >> 6;
  const int lane = threadIdx.x & 63;
  const long t = (long)blockIdx.x * 4 + wv;
  const float* row = X + t * 512;
  const float4 a = *(const float4*)(row + lane * 8);
  const float4 c = *(const float4*)(row + lane * 8 + 4);
  float s  = a.x + a.y + a.z + a.w + c.x + c.y + c.z + c.w;
  float ss = a.x*a.x + a.y*a.y + a.z*a.z + a.w*a.w + c.x*c.x + c.y*c.y + c.z*c.z + c.w*c.w;
  #pragma unroll
  for (int m_ = 32; m_ > 0; m_ >>= 1) { s += __shfl_xor(s, m_); ss += __shfl_xor(ss, m_); }
  if (lane == 0) {
    const float m = s * (1.f / 512.f);
    const float var = ss * (1.f / 512.f) - m * m;
    mu[t] = m; rs[t] = rsqrtf(var + EPS_);
  }
}

// ---------- LN2 apply -> fp8 tokens ----------
__global__ __launch_bounds__(256)
void ln2_apply(const float* __restrict__ X, const float* __restrict__ mu,
               const float* __restrict__ rs, const float* __restrict__ w,
               const float* __restrict__ bb, uint8_t* __restrict__ Z) {
  const long i = ((long)blockIdx.x * 256 + threadIdx.x) * 4;
  const int t = (int)(i >> 9);
  const int c = (int)(i & 511);
  const float m = mu[t], r = rs[t];
  const float4 v = *(const float4*)(X + i);
  float v0 = (v.x - m) * r * w[c + 0] + bb[c + 0];
  float v1 = (v.y - m) * r * w[c + 1] + bb[c + 1];
  float v2 = (v.z - m) * r * w[c + 2] + bb[c + 2];
  float v3 = (v.w - m) * r * w[c + 3] + bb[c + 3];
  *(int*)(Z + i) = pk_fp8x4(v0, v1, v2, v3);
}

// ---------- fp8 MFMA GEMM, A (M,K) row-major, B (N,K) row-major, 128x128 tile, BK=64 ----------
// LDS layout (both tiles): addr(row,q,ks) = ks*4096 + row*32 + q*8  -> frag ds_read_b64 conflict-free
// B column permutation: LDS row_slot s holds weight row n0 + (s&~63) + (s&15)*4 + ((s>>4)&3)
//   => acc[.][j] lane(lm) covers output col n0+wn+lm*4+j  => 4 consecutive cols per lane
// EPI 0: qkv  out_fp8 = (acc+bias)*(col<512 ? qscale : 1)
// EPI 1: proj out_f32 = res + gamma*(acc+bias)
// EPI 2: fc1  out_fp8 = gelu_exact(acc+bias)
// EPI 3: fc2  out_f32 = res + gamma*(acc+bias)
template<int EPI>
__global__ __launch_bounds__(256)
void gemm_fp8(const uint8_t* __restrict__ A, const uint8_t* __restrict__ Bw,
              const float* __restrict__ bias, const float* __restrict__ res,
              const float* __restrict__ gamma,
              uint8_t* __restrict__ outb, float* __restrict__ outf,
              const int K, const int N) {
  __shared__ uint8_t As[8192];
  __shared__ uint8_t Bs[8192];
  const int tid = threadIdx.x;
  const int wave = tid >> 6, lane = tid & 63;
  const int lm = lane & 15, lq = lane >> 4;
  const long m0 = (long)blockIdx.x * 128;
  const long n0 = (long)blockIdx.y * 128;
  const int srow = tid >> 1;
  const int half16 = (tid & 1) << 4;
  const uint8_t* ag = A + (m0 + srow) * K + half16;
  const int wrow = (srow & ~63) + (srow & 15) * 4 + ((srow >> 4) & 3);
  const uint8_t* bg = Bw + (n0 + wrow) * K + half16;
  uint8_t* lA0 = As + tid * 16;
  uint8_t* lA1 = As + 4096 + tid * 16;
  uint8_t* lB0 = Bs + tid * 16;
  uint8_t* lB1 = Bs + 4096 + tid * 16;
  const int wm = (wave >> 1) << 6;
  const int wn = (wave & 1) << 6;
  floatx4 acc[4][4] = {};
  const int nk = K >> 6;
  for (int kt = 0; kt < nk; ++kt) {
    gload16(ag, lA0);
    gload16(ag + 32, lA1);
    gload16(bg, lB0);
    gload16(bg + 32, lB1);
    __syncthreads();
    #pragma unroll
    for (int ks = 0; ks < 2; ++ks) {
      long af[4], bfv[4];
      #pragma unroll
      for (int i = 0; i < 4; ++i)
        af[i] = *(const long*)(As + ks * 4096 + (wm + i * 16 + lm) * 32 + lq * 8);
      #pragma unroll
      for (int j = 0; j < 4; ++j)
        bfv[j] = *(const long*)(Bs + ks * 4096 + (wn + j * 16 + lm) * 32 + lq * 8);
      #pragma unroll
      for (int i = 0; i < 4; ++i)
        #pragma unroll
        for (int j = 0; j < 4; ++j)
          acc[i][j] = __builtin_amdgcn_mfma_f32_16x16x32_fp8_fp8(af[i], bfv[j], acc[i][j], 0, 0, 0);
    }
    __syncthreads();
    ag += 64; bg += 64;
  }
  // epilogue: lane owns cols cb..cb+3, rows wm+i*16+lq*4+r
  const int cb = (int)n0 + wn + lm * 4;
  const float4 b4 = *(const float4*)(bias + cb);
  float4 g4 = make_float4(0.f, 0.f, 0.f, 0.f);
  if (EPI == 1 || EPI == 3) g4 = *(const float4*)(gamma + cb);
  const float qs = (EPI == 0 && cb < 512) ? QSCALE : 1.f;
  #pragma unroll
  for (int i = 0; i < 4; ++i) {
    #pragma unroll
    for (int r = 0; r < 4; ++r) {
      const long rowg = m0 + wm + i * 16 + lq * 4 + r;
      float v0 = acc[i][0][r] + b4.x;
      float v1 = acc[i][1][r] + b4.y;
      float v2 = acc[i][2][r] + b4.z;
      float v3 = acc[i][3][r] + b4.w;
      if (EPI == 0) {
        *(int*)(outb + rowg * (long)N + cb) = pk_fp8x4(v0 * qs, v1 * qs, v2 * qs, v3 * qs);
      } else if (EPI == 2) {
        v0 = 0.5f * v0 * (1.f + erff(v0 * 0.70710678118654752f));
        v1 = 0.5f * v1 * (1.f + erff(v1 * 0.70710678118654752f));
        v2 = 0.5f * v2 * (1.f + erff(v2 * 0.70710678118654752f));
        v3 = 0.5f * v3 * (1.f + erff(v3 * 0.70710678118654752f));
        *(int*)(outb + rowg * (long)N + cb) = pk_fp8x4(v0, v1, v2, v3);
      } else {
        const long o = rowg * (long)N + cb;
        const float4 rv = *(const float4*)(res + o);
        float4 ov;
        ov.x = rv.x + g4.x * v0;
        ov.y = rv.y + g4.y * v1;
        ov.z = rv.z + g4.z * v2;
        ov.w = rv.w + g4.w * v3;
        *(float4*)(outf + o) = ov;
      }
    }
  }
}

// ---------- windowed attention: one wave per (window, head); lane = query row ----------
__global__ __launch_bounds__(256)
void attn_kern(const uint8_t* __restrict__ QKV, const float* __restrict__ rel_bias,
               uint8_t* __restrict__ AT) {
  __shared__ float kvs[4][2][NWIN * 32];   // per-wave K and V, 50176 B total
  const int wave = threadIdx.x >> 6;
  const int lane = threadIdx.x & 63;
  const int gw = blockIdx.x * 4 + wave;    // [0, 8192)
  const int wd = gw >> 4;                  // window id [0, 512)
  const int head = gw & 15;
  const int b = wd >> 2;
  const int wi = (wd >> 1) & 1;
  const int wj = wd & 1;
  float* ks = kvs[wave][0];
  float* vs = kvs[wave][1];
  const long qkvbase = (long)b * 196 * 1536;
  // stage K,V (shift map folded into addressing)
  for (int idx8 = lane; idx8 < 196; idx8 += 64) {
    const int n = idx8 >> 2;
    const int d0 = (idx8 & 3) << 3;
    const int ti_ = n / 7, tj_ = n - ti_ * 7;
    int h = wi * 7 + ti_ + 3; if (h >= 14) h -= 14;
    int w = wj * 7 + tj_ + 3; if (w >= 14) w -= 14;
    const uint8_t* kp = QKV + qkvbase + (long)(h * 14 + w) * 1536 + 512 + head * 32 + d0;
    const uint2 kk = *(const uint2*)kp;
    const uint2 vv = *(const uint2*)(kp + 512);
    float* kd = ks + n * 32 + d0;
    float* vd = vs + n * 32 + d0;
    up_fp8x4(kk.x, kd);     up_fp8x4(kk.y, kd + 4);
    up_fp8x4(vv.x, vd);     up_fp8x4(vv.y, vd + 4);
  }
  // per-lane q (lanes >=49 clamp to 48, never store)
  const int li = lane < 49 ? lane : 48;
  const int ti = li / 7, tj = li - (li / 7) * 7;
  int h = wi * 7 + ti + 3; if (h >= 14) h -= 14;
  int w = wj * 7 + tj + 3; if (w >= 14) w -= 14;
  const long t_i = (long)b * 196 + h * 14 + w;
  float q[32];
  {
    const uint8_t* qp = QKV + t_i * 1536 + head * 32;   // q pre-scaled in qkv epilogue
    const uint4 q0 = *(const uint4*)qp;
    const uint4 q1 = *(const uint4*)(qp + 16);
    up_fp8x4(q0.x, q + 0);  up_fp8x4(q0.y, q + 4);
    up_fp8x4(q0.z, q + 8);  up_fp8x4(q0.w, q + 12);
    up_fp8x4(q1.x, q + 16); up_fp8x4(q1.y, q + 20);
    up_fp8x4(q1.z, q + 24); up_fp8x4(q1.w, q + 28);
  }
  const int hh = wi * 7 + ti, ww = wj * 7 + tj;        // unshifted coords for mask regions
  const int ri = (hh < 7 ? 0 : (hh < 11 ? 1 : 2)) * 3 + (ww < 7 ? 0 : (ww < 11 ? 1 : 2));
  __syncthreads();
  // pass 1: scores + bias + mask
  float s[NWIN];
  float mx = -1e30f;
  #pragma unroll
  for (int j = 0; j < NWIN; ++j) {
    const float* kr = ks + j * 32;
    float a = 0.f;
    #pragma unroll
    for (int dd = 0; dd < 32; dd += 4) {
      const float4 kk = *(const float4*)(kr + dd);
      a += q[dd] * kk.x + q[dd + 1] * kk.y + q[dd + 2] * kk.z + q[dd + 3] * kk.w;
    }
    const int sjt = j / 7, sjc = j - sjt * 7;
    const int bidx = (ti - sjt + 6) * 13 + (tj - sjc + 6);
    const float bias = rel_bias[bidx * 16 + head];
    const int h2 = wi * 7 + sjt, w2 = wj * 7 + sjc;
    const int rj = (h2 < 7 ? 0 : (h2 < 11 ? 1 : 2)) * 3 + (w2 < 7 ? 0 : (w2 < 11 ? 1 : 2));
    const float sv = a + bias + ((ri != rj) ? -100.f : 0.f);
    s[j] = sv;
    mx = fmaxf(mx, sv);
  }
  float sum = 0.f;
  #pragma unroll
  for (int j = 0; j < NWIN; ++j) { const float e = __expf(s[j] - mx); s[j] = e; sum += e; }
  const float inv = 1.f / sum;
  // pass 2: P @ V
  float oacc[32] = {};
  #pragma unroll
  for (int j = 0; j < NWIN; ++j) {
    const float p = s[j];
    const float* vr = vs + j * 32;
    #pragma unroll
    for (int dd = 0; dd < 32; dd += 4) {
      const float4 vv = *(const float4*)(vr + dd);
      oacc[dd] += p * vv.x; oacc[dd + 1] += p * vv.y;
      oacc[dd + 2] += p * vv.z; oacc[dd + 3] += p * vv.w;
    }
  }
  if (lane < 49) {
    uint8_t* op = AT + t_i * 512 + head * 32;
    int ow[8];
    #pragma unroll
    for (int d8 = 0; d8 < 8; ++d8) {
      ow[d8] = pk_fp8x4(oacc[d8 * 4 + 0] * inv, oacc[d8 * 4 + 1] * inv,
                        oacc[d8 * 4 + 2] * inv, oacc[d8 * 4 + 3] * inv);
    }
    *(int4*)op = make_int4(ow[0], ow[1], ow[2], ow[3]);
    *(int4*)(op + 16) = make_int4(ow[4], ow[5], ow[6], ow[7]);
  }
}

// ---------- final token-major f32 -> NCHW ----------
__global__ __launch_bounds__(256)
void out_transpose(const float* __restrict__ F, float* __restrict__ out) {
  __shared__ float tile[49][65];
  const int bid = blockIdx.x;
  const int ct = bid & 7;
  const int pt = (bid >> 3) & 3;
  const int b = bid >> 5;
  const int p0 = pt * 49, c0 = ct * 64;
  const int tbase = b * 196 + p0;
  for (int idx = threadIdx.x; idx < 3136; idx += 256) {
    const int pl = idx >> 6;
    const int cl = idx & 63;
    tile[pl][cl] = F[(long)(tbase + pl) * 512 + c0 + cl];
  }
  __syncthreads();
  const long obase = (long)b * 100352;
  for (int idx = threadIdx.x; idx < 3136; idx += 256) {
    const int cl = idx / 49;
    const int pl = idx - cl * 49;
    out[obase + (long)(c0 + cl) * 196 + p0 + pl] = tile[pl][cl];
  }
}

extern "C" void kernel_launch(void* const* d_in, const int* in_sizes, int n_in,
                              void* d_out, int out_size, void* d_ws, size_t ws_size,
                              hipStream_t stream) {
  const float* x      = (const float*)d_in[0];
  const float* ln1_w  = (const float*)d_in[1];
  const float* ln1_b  = (const float*)d_in[2];
  const float* qkv_w  = (const float*)d_in[3];
  const float* qkv_b  = (const float*)d_in[4];
  const float* relb   = (const float*)d_in[5];
  const float* proj_w = (const float*)d_in[6];
  const float* proj_b = (const float*)d_in[7];
  const float* gamma1 = (const float*)d_in[8];
  const float* ln2_w  = (const float*)d_in[9];
  const float* ln2_b  = (const float*)d_in[10];
  const float* fc1_w  = (const float*)d_in[11];
  const float* fc1_b  = (const float*)d_in[12];
  const float* fc2_w  = (const float*)d_in[13];
  const float* fc2_b  = (const float*)d_in[14];
  const float* gamma2 = (const float*)d_in[15];
  float* out = (float*)d_out;
  char* ws = (char*)d_ws;

  float*   mu1 = (float*)(ws + 0);
  float*   rs1 = (float*)(ws + 100352);
  float*   mu2 = (float*)(ws + 200704);
  float*   rs2 = (float*)(ws + 301056);
  uint8_t* Wq  = (uint8_t*)(ws + 401408);    //   786,432 B
  uint8_t* Wp  = (uint8_t*)(ws + 1187840);   //   262,144 B
  uint8_t* W1  = (uint8_t*)(ws + 1449984);   // 1,048,576 B
  uint8_t* W2  = (uint8_t*)(ws + 2498560);   // 1,048,576 B
  uint8_t* Afp = (uint8_t*)(ws + 3547136);   // 12,845,056 B (LN1 tokens, later LN2 tokens)
  float*   XT  = (float*)  (ws + 16392192);  // 51,380,224 B raw x token-major
  float*   X1  = (float*)  (ws + 67772416);  // 51,380,224 B
  uint8_t* QKV = (uint8_t*)(ws + 119152640); // 38,535,168 B
  uint8_t* AT  = (uint8_t*)(ws + 157687808); // 12,845,056 B
  uint8_t* Hb  = (uint8_t*)(ws + 119152640); // 51,380,224 B overlaps dead QKV+AT exactly

  // weights -> fp8
  cvt_fp8<<<768,  256, 0, stream>>>(qkv_w, Wq, 196608);
  cvt_fp8<<<256,  256, 0, stream>>>(proj_w, Wp, 65536);
  cvt_fp8<<<1024, 256, 0, stream>>>(fc1_w, W1, 262144);
  cvt_fp8<<<1024, 256, 0, stream>>>(fc2_w, W2, 262144);

  // LN1 + transpose to token-major
  ln_stats_nchw<<<392, 256, 0, stream>>>(x, mu1, rs1);
  ln1_apply<<<4096, 256, 0, stream>>>(x, mu1, rs1, ln1_w, ln1_b, XT, Afp);

  // qkv GEMM (q pre-scaled)
  gemm_fp8<0><<<dim3(196, 12), 256, 0, stream>>>(Afp, Wq, qkv_b, nullptr, nullptr, QKV, nullptr, 512, 1536);

  // shifted-window attention
  attn_kern<<<2048, 256, 0, stream>>>(QKV, relb, AT);

  // proj GEMM, fused X1 = x + g1*(out+b)
  gemm_fp8<1><<<dim3(196, 4), 256, 0, stream>>>(AT, Wp, proj_b, XT, gamma1, nullptr, X1, 512, 512);

  // LN2
  ln_stats_row<<<6272, 256, 0, stream>>>(X1, mu2, rs2);
  ln2_apply<<<12544, 256, 0, stream>>>(X1, mu2, rs2, ln2_w, ln2_b, Afp);

  // MLP
  gemm_fp8<2><<<dim3(196, 16), 256, 0, stream>>>(Afp, W1, fc1_b, nullptr, nullptr, Hb, nullptr, 512, 2048);
  gemm_fp8<3><<<dim3(196, 4), 256, 0, stream>>>(Hb, W2, fc2_b, X1, gamma2, nullptr, X1, 2048, 512);

  // token-major -> NCHW
  out_transpose<<<4096, 256, 0, stream>>>(X1, out);
}

// Round 4
// 495.564 us; speedup vs baseline: 1.2961x; 1.1723x over previous
//
#include <hip/hip_runtime.h>
#include <cmath>
#include <cstdint>

typedef float floatx4 __attribute__((ext_vector_type(4)));
typedef float floatx2 __attribute__((ext_vector_type(2)));

#define EPS_ 1e-5f
#define QSCALE 0.17677669529663689f
#define NWIN 49

// ---------- async global->LDS (16B per lane) ----------
__device__ __forceinline__ void gload16(const uint8_t* g, uint8_t* l) {
  __builtin_amdgcn_global_load_lds(
      (const __attribute__((address_space(1))) void*)g,
      (__attribute__((address_space(3))) void*)l, 16, 0, 0);
}

// ---------- fp8 e4m3 pack/unpack (word-select must be an immediate) ----------
template<bool HI>
__device__ __forceinline__ int pk_fp8(float a, float b, int old) {
  return __builtin_amdgcn_cvt_pk_fp8_f32(a, b, old, HI);
}
__device__ __forceinline__ int pk_fp8x4(float v0, float v1, float v2, float v3) {
  int w = pk_fp8<false>(v0, v1, 0);
  return pk_fp8<true>(v2, v3, w);
}

// ---------- fp32 -> fp8 weight conversion (4 floats -> 1 dword) ----------
__global__ void cvt_fp8(const float* __restrict__ s, uint8_t* __restrict__ d, int n4) {
  int i = blockIdx.x * 256 + threadIdx.x;
  if (i < n4) {
    float4 v = ((const float4*)s)[i];
    ((int*)d)[i] = pk_fp8x4(v.x, v.y, v.z, v.w);
  }
}

// ---------- LN1 stats over C for NCHW input ----------
__global__ __launch_bounds__(256)
void ln_stats_nchw(const float* __restrict__ x, float* __restrict__ mu, float* __restrict__ rs) {
  const int tl = threadIdx.x & 63;
  const int wv = threadIdx.x >> 6;
  const int t = blockIdx.x * 64 + tl;       // token = b*196 + p
  const int b = t / 196;
  const int p = t - b * 196;
  const float* xp = x + (long)b * 100352 + p;
  float s = 0.f, ss = 0.f;
  const int cbeg = wv * 128;
  for (int c = cbeg; c < cbeg + 128; ++c) {
    const float v = xp[(long)c * 196];
    s += v; ss += v * v;
  }
  __shared__ float sb[4][64], qb[4][64];
  sb[wv][tl] = s; qb[wv][tl] = ss;
  __syncthreads();
  if (wv == 0) {
    s  = sb[0][tl] + sb[1][tl] + sb[2][tl] + sb[3][tl];
    ss = qb[0][tl] + qb[1][tl] + qb[2][tl] + qb[3][tl];
    const float m = s * (1.f / 512.f);
    const float var = ss * (1.f / 512.f) - m * m;
    mu[t] = m;
    rs[t] = rsqrtf(var + EPS_);
  }
}

// ---------- LN1 apply + NCHW->token-major transpose; writes XT (raw x, f32) and A (normalized, fp8) ----------
__global__ __launch_bounds__(256)
void ln1_apply(const float* __restrict__ x, const float* __restrict__ mu, const float* __restrict__ rs,
               const float* __restrict__ w, const float* __restrict__ bb,
               float* __restrict__ XT, uint8_t* __restrict__ A) {
  __shared__ float tile[64][53];            // 53: gcd(53,32)=1 -> conflict-free
  const int bid = blockIdx.x;
  const int ct = bid & 7;
  const int pt = (bid >> 3) & 3;
  const int b = bid >> 5;
  const int p0 = pt * 49, c0 = ct * 64;
  const long xbase = (long)b * 100352;
  for (int idx = threadIdx.x; idx < 3136; idx += 256) {
    const int cl = idx / 49;
    const int pl = idx - cl * 49;
    tile[cl][pl] = x[xbase + (long)(c0 + cl) * 196 + p0 + pl];
  }
  __syncthreads();
  const int tbase = b * 196 + p0;
  for (int idx = threadIdx.x; idx < 3136; idx += 256) {
    const int pl = idx >> 6;
    const int cl = idx & 63;
    const int t = tbase + pl;
    XT[(long)t * 512 + c0 + cl] = tile[cl][pl];
  }
  for (int idx = threadIdx.x; idx < 784; idx += 256) {
    const int pl = idx >> 4;                // 0..48
    const int cq = (idx & 15) << 2;         // 0..60 step 4
    const int t = tbase + pl;
    const float m = mu[t], rr = rs[t];
    float v0 = (tile[cq + 0][pl] - m) * rr * w[c0 + cq + 0] + bb[c0 + cq + 0];
    float v1 = (tile[cq + 1][pl] - m) * rr * w[c0 + cq + 1] + bb[c0 + cq + 1];
    float v2 = (tile[cq + 2][pl] - m) * rr * w[c0 + cq + 2] + bb[c0 + cq + 2];
    float v3 = (tile[cq + 3][pl] - m) * rr * w[c0 + cq + 3] + bb[c0 + cq + 3];
    *(int*)(A + (long)t * 512 + c0 + cq) = pk_fp8x4(v0, v1, v2, v3);
  }
}

// ---------- LN2 stats (token-major f32 rows) ----------
__global__ __launch_bounds__(256)
void ln_stats_row(const float* __restrict__ X, float* __restrict__ mu, float* __restrict__ rs) {
  const int wv = threadIdx.x >> 6;
  const int lane = threadIdx.x & 63;
  const long t = (long)blockIdx.x * 4 + wv;
  const float* row = X + t * 512;
  const float4 a = *(const float4*)(row + lane * 8);
  const float4 c = *(const float4*)(row + lane * 8 + 4);
  float s  = a.x + a.y + a.z + a.w + c.x + c.y + c.z + c.w;
  float ss = a.x*a.x + a.y*a.y + a.z*a.z + a.w*a.w + c.x*c.x + c.y*c.y + c.z*c.z + c.w*c.w;
  #pragma unroll
  for (int m_ = 32; m_ > 0; m_ >>= 1) { s += __shfl_xor(s, m_); ss += __shfl_xor(ss, m_); }
  if (lane == 0) {
    const float m = s * (1.f / 512.f);
    const float var = ss * (1.f / 512.f) - m * m;
    mu[t] = m; rs[t] = rsqrtf(var + EPS_);
  }
}

// ---------- LN2 apply -> fp8 tokens ----------
__global__ __launch_bounds__(256)
void ln2_apply(const float* __restrict__ X, const float* __restrict__ mu,
               const float* __restrict__ rs, const float* __restrict__ w,
               const float* __restrict__ bb, uint8_t* __restrict__ Z) {
  const long i = ((long)blockIdx.x * 256 + threadIdx.x) * 4;
  const int t = (int)(i >> 9);
  const int c = (int)(i & 511);
  const float m = mu[t], r = rs[t];
  const float4 v = *(const float4*)(X + i);
  float v0 = (v.x - m) * r * w[c + 0] + bb[c + 0];
  float v1 = (v.y - m) * r * w[c + 1] + bb[c + 1];
  float v2 = (v.z - m) * r * w[c + 2] + bb[c + 2];
  float v3 = (v.w - m) * r * w[c + 3] + bb[c + 3];
  *(int*)(Z + i) = pk_fp8x4(v0, v1, v2, v3);
}

// ---------- fp8 MFMA GEMM, A (M,K) row-major, B (N,K) row-major, 128x128 tile, BK=64 ----------
template<int EPI>
__global__ __launch_bounds__(256)
void gemm_fp8(const uint8_t* __restrict__ A, const uint8_t* __restrict__ Bw,
              const float* __restrict__ bias, const float* __restrict__ res,
              const float* __restrict__ gamma,
              uint8_t* __restrict__ outb, float* __restrict__ outf,
              const int K, const int N) {
  __shared__ uint8_t As[8192];
  __shared__ uint8_t Bs[8192];
  const int tid = threadIdx.x;
  const int wave = tid >> 6, lane = tid & 63;
  const int lm = lane & 15, lq = lane >> 4;
  const long m0 = (long)blockIdx.x * 128;
  const long n0 = (long)blockIdx.y * 128;
  const int srow = tid >> 1;
  const int half16 = (tid & 1) << 4;
  const uint8_t* ag = A + (m0 + srow) * K + half16;
  const int wrow = (srow & ~63) + (srow & 15) * 4 + ((srow >> 4) & 3);
  const uint8_t* bg = Bw + (n0 + wrow) * K + half16;
  uint8_t* lA0 = As + tid * 16;
  uint8_t* lA1 = As + 4096 + tid * 16;
  uint8_t* lB0 = Bs + tid * 16;
  uint8_t* lB1 = Bs + 4096 + tid * 16;
  const int wm = (wave >> 1) << 6;
  const int wn = (wave & 1) << 6;
  floatx4 acc[4][4] = {};
  const int nk = K >> 6;
  for (int kt = 0; kt < nk; ++kt) {
    gload16(ag, lA0);
    gload16(ag + 32, lA1);
    gload16(bg, lB0);
    gload16(bg + 32, lB1);
    __syncthreads();
    #pragma unroll
    for (int ks = 0; ks < 2; ++ks) {
      long af[4], bfv[4];
      #pragma unroll
      for (int i = 0; i < 4; ++i)
        af[i] = *(const long*)(As + ks * 4096 + (wm + i * 16 + lm) * 32 + lq * 8);
      #pragma unroll
      for (int j = 0; j < 4; ++j)
        bfv[j] = *(const long*)(Bs + ks * 4096 + (wn + j * 16 + lm) * 32 + lq * 8);
      #pragma unroll
      for (int i = 0; i < 4; ++i)
        #pragma unroll
        for (int j = 0; j < 4; ++j)
          acc[i][j] = __builtin_amdgcn_mfma_f32_16x16x32_fp8_fp8(af[i], bfv[j], acc[i][j], 0, 0, 0);
    }
    __syncthreads();
    ag += 64; bg += 64;
  }
  const int cb = (int)n0 + wn + lm * 4;
  const float4 b4 = *(const float4*)(bias + cb);
  float4 g4 = make_float4(0.f, 0.f, 0.f, 0.f);
  if (EPI == 1 || EPI == 3) g4 = *(const float4*)(gamma + cb);
  const float qs = (EPI == 0 && cb < 512) ? QSCALE : 1.f;
  #pragma unroll
  for (int i = 0; i < 4; ++i) {
    #pragma unroll
    for (int r = 0; r < 4; ++r) {
      const long rowg = m0 + wm + i * 16 + lq * 4 + r;
      float v0 = acc[i][0][r] + b4.x;
      float v1 = acc[i][1][r] + b4.y;
      float v2 = acc[i][2][r] + b4.z;
      float v3 = acc[i][3][r] + b4.w;
      if (EPI == 0) {
        *(int*)(outb + rowg * (long)N + cb) = pk_fp8x4(v0 * qs, v1 * qs, v2 * qs, v3 * qs);
      } else if (EPI == 2) {
        v0 = 0.5f * v0 * (1.f + erff(v0 * 0.70710678118654752f));
        v1 = 0.5f * v1 * (1.f + erff(v1 * 0.70710678118654752f));
        v2 = 0.5f * v2 * (1.f + erff(v2 * 0.70710678118654752f));
        v3 = 0.5f * v3 * (1.f + erff(v3 * 0.70710678118654752f));
        *(int*)(outb + rowg * (long)N + cb) = pk_fp8x4(v0, v1, v2, v3);
      } else {
        const long o = rowg * (long)N + cb;
        const float4 rv = *(const float4*)(res + o);
        float4 ov;
        ov.x = rv.x + g4.x * v0;
        ov.y = rv.y + g4.y * v1;
        ov.z = rv.z + g4.z * v2;
        ov.w = rv.w + g4.w * v3;
        *(float4*)(outf + o) = ov;
      }
    }
  }
}

// ---------- BM table: bias+mask+padding in MFMA C-layout order ----------
// BM[head][wpos][qi*4+ti][lane][r]  (1 MB total)
__global__ __launch_bounds__(256)
void bm_build(const float* __restrict__ rel_bias, float* __restrict__ BM) {
  const int hw = blockIdx.x;           // head*4 + wpos
  const int head = hw >> 2, wpos = hw & 3;
  const int wi = wpos >> 1, wj = wpos & 1;
  for (int k = 0; k < 4; ++k) {
    const int idx = k * 256 + threadIdx.x;   // tile*64 + lane
    const int tile = idx >> 6, l = idx & 63;
    const int qi = tile >> 2, ti = tile & 3;
    const int n = l & 15, g = l >> 4;
    const int query = qi * 16 + n;
    const int qy = query / 7, qx = query - qy * 7;
    const int hh = wi * 7 + qy, ww = wj * 7 + qx;
    const int ri = (hh < 7 ? 0 : (hh < 11 ? 1 : 2)) * 3 + (ww < 7 ? 0 : (ww < 11 ? 1 : 2));
    float4 ov;
    float vv[4];
    #pragma unroll
    for (int r = 0; r < 4; ++r) {
      const int key = ti * 16 + g * 4 + r;
      float v;
      if (query >= 49 || key >= 49) {
        v = -3.0e38f;
      } else {
        const int ky = key / 7, kx = key - ky * 7;
        const int bidx = (qy - ky + 6) * 13 + (qx - kx + 6);
        const int h2 = wi * 7 + ky, w2 = wj * 7 + kx;
        const int rj = (h2 < 7 ? 0 : (h2 < 11 ? 1 : 2)) * 3 + (w2 < 7 ? 0 : (w2 < 11 ? 1 : 2));
        v = rel_bias[bidx * 16 + head] + ((ri != rj) ? -100.f : 0.f);
      }
      vv[r] = v;
    }
    ov.x = vv[0]; ov.y = vv[1]; ov.z = vv[2]; ov.w = vv[3];
    *(float4*)(BM + ((long)(hw * 16 + tile) << 8) + l * 4) = ov;
  }
}

// ---------- 4x4 byte transpose ----------
__device__ __forceinline__ void tr4(const uint32_t d[4], uint32_t o[4]) {
  #pragma unroll
  for (int c = 0; c < 4; ++c)
    o[c] = ((d[0] >> (8 * c)) & 0xffu) | (((d[1] >> (8 * c)) & 0xffu) << 8)
         | (((d[2] >> (8 * c)) & 0xffu) << 16) | (((d[3] >> (8 * c)) & 0xffu) << 24);
}

// ---------- MFMA windowed attention: one wave per (window, head) ----------
// S^T = K·Q^T (16 mfma, C init = BM), softmax per query col, P fp8 -> LDS,
// O = P·V (16 mfma) with V transposed to [dim][token] in LDS. Wave-private LDS, no barriers.
__global__ __launch_bounds__(256)
void attn_mfma(const uint8_t* __restrict__ QKV, const float* __restrict__ BM,
               uint8_t* __restrict__ AT) {
  __shared__ uint8_t lds[4][9984];   // per-wave: Pb 64x72, Vt 32x72, Ot 64x48
  const int wave = threadIdx.x >> 6, lane = threadIdx.x & 63;
  const int n = lane & 15, g = lane >> 4;
  const int gw = blockIdx.x * 4 + wave;
  const int wd = gw >> 4, head = gw & 15;
  const int b = wd >> 2, wpos = wd & 3;
  const int wi = wpos >> 1, wj = wpos & 1;
  uint8_t* Pb = lds[wave];
  uint8_t* Vt = lds[wave] + 4608;
  uint8_t* Ot = lds[wave] + 6912;
  const long base = (long)b * 196 * 1536;
  auto tok = [&](int slot) -> int {
    const int ty = slot / 7, tx = slot - ty * 7;
    int h = wi * 7 + ty + 3; if (h >= 14) h -= 14;
    int w = wj * 7 + tx + 3; if (w >= 14) w -= 14;
    return h * 14 + w;
  };
  // Q/K fragments: direct global b64 loads (row-major token x dim)
  long Ak[4], Bq[4];
  #pragma unroll
  for (int t4 = 0; t4 < 4; ++t4) {
    int slot = t4 * 16 + n; if (slot > 48) slot = 48;
    const long tb = base + (long)tok(slot) * 1536 + head * 32 + g * 8;
    Bq[t4] = *(const long*)(QKV + tb);          // Q rows (B operand)
    Ak[t4] = *(const long*)(QKV + tb + 512);    // K rows (A operand)
  }
  // V: transpose 4x4 byte blocks into Vt[dim][token], stride 72
  #pragma unroll
  for (int bb2 = 0; bb2 < 2; ++bb2) {
    const int blk = lane + bb2 * 64;
    const int dq = blk >> 4, tq = blk & 15;
    uint32_t d4[4], o4[4];
    #pragma unroll
    for (int r = 0; r < 4; ++r) {
      int slot = tq * 4 + r; if (slot > 48) slot = 48;
      d4[r] = *(const uint32_t*)(QKV + base + (long)tok(slot) * 1536 + 1024 + head * 32 + dq * 4);
    }
    tr4(d4, o4);
    #pragma unroll
    for (int c = 0; c < 4; ++c)
      *(uint32_t*)(Vt + (dq * 4 + c) * 72 + tq * 4) = o4[c];
  }
  // acc init from BM (bias+mask+padding, already in C-layout order)
  floatx4 acc[4][4];
  const float* bmw = BM + ((long)(head * 4 + wpos) << 12) + lane * 4;
  #pragma unroll
  for (int qi = 0; qi < 4; ++qi)
    #pragma unroll
    for (int ti = 0; ti < 4; ++ti) {
      const float4 bv = *(const float4*)(bmw + ((qi * 4 + ti) << 8));
      acc[qi][ti][0] = bv.x; acc[qi][ti][1] = bv.y;
      acc[qi][ti][2] = bv.z; acc[qi][ti][3] = bv.w;
    }
  // S^T = K·Q^T  (D[m=key][n=query])
  #pragma unroll
  for (int qi = 0; qi < 4; ++qi)
    #pragma unroll
    for (int ti = 0; ti < 4; ++ti)
      acc[qi][ti] = __builtin_amdgcn_mfma_f32_16x16x32_fp8_fp8(Ak[ti], Bq[qi], acc[qi][ti], 0, 0, 0);
  // softmax over keys for query col n (16 in-lane + xor16/32), write normalized P fp8
  #pragma unroll
  for (int qi = 0; qi < 4; ++qi) {
    float mx = -3.0e38f;
    #pragma unroll
    for (int ti = 0; ti < 4; ++ti)
      #pragma unroll
      for (int r = 0; r < 4; ++r) mx = fmaxf(mx, acc[qi][ti][r]);
    mx = fmaxf(mx, __shfl_xor(mx, 16));
    mx = fmaxf(mx, __shfl_xor(mx, 32));
    float sum = 0.f;
    #pragma unroll
    for (int ti = 0; ti < 4; ++ti)
      #pragma unroll
      for (int r = 0; r < 4; ++r) {
        const float e = __expf(acc[qi][ti][r] - mx);
        acc[qi][ti][r] = e; sum += e;
      }
    sum += __shfl_xor(sum, 16);
    sum += __shfl_xor(sum, 32);
    const float inv = 1.f / sum;
    #pragma unroll
    for (int ti = 0; ti < 4; ++ti) {
      const int pw = pk_fp8x4(acc[qi][ti][0] * inv, acc[qi][ti][1] * inv,
                              acc[qi][ti][2] * inv, acc[qi][ti][3] * inv);
      *(uint32_t*)(Pb + (qi * 16 + n) * 72 + ti * 16 + g * 4) = pw;
    }
  }
  asm volatile("s_waitcnt lgkmcnt(0)" ::: "memory");
  // O = P·V  (A = P rows [query][key], B = Vt rows [dim][key])
  long Bv[2][2];
  #pragma unroll
  for (int ni = 0; ni < 2; ++ni)
    #pragma unroll
    for (int s = 0; s < 2; ++s)
      Bv[ni][s] = *(const long*)(Vt + (ni * 16 + n) * 72 + s * 32 + g * 8);
  floatx4 o[4][2] = {};
  #pragma unroll
  for (int qi = 0; qi < 4; ++qi)
    #pragma unroll
    for (int s = 0; s < 2; ++s) {
      const long Ap = *(const long*)(Pb + (qi * 16 + n) * 72 + s * 32 + g * 8);
      #pragma unroll
      for (int ni = 0; ni < 2; ++ni)
        o[qi][ni] = __builtin_amdgcn_mfma_f32_16x16x32_fp8_fp8(Ap, Bv[ni][s], o[qi][ni], 0, 0, 0);
    }
  // O (C-layout: row=query, col=dim) -> Ot bytes, then coalesced token-major store
  #pragma unroll
  for (int qi = 0; qi < 4; ++qi)
    #pragma unroll
    for (int ni = 0; ni < 2; ++ni)
      #pragma unroll
      for (int r = 0; r < 4; ++r)
        Ot[(qi * 16 + g * 4 + r) * 48 + ni * 16 + n] =
            (uint8_t)(pk_fp8<false>(o[qi][ni][r], 0.f, 0) & 0xff);
  asm volatile("s_waitcnt lgkmcnt(0)" ::: "memory");
  if (lane < 49) {
    const int t = tok(lane);
    uint8_t* op = AT + ((long)b * 196 + t) * 512 + head * 32;
    const int4 w0 = *(const int4*)(Ot + lane * 48);
    const int4 w1 = *(const int4*)(Ot + lane * 48 + 16);
    *(int4*)op = w0;
    *(int4*)(op + 16) = w1;
  }
}

// ---------- final token-major f32 -> NCHW ----------
__global__ __launch_bounds__(256)
void out_transpose(const float* __restrict__ F, float* __restrict__ out) {
  __shared__ float tile[49][65];
  const int bid = blockIdx.x;
  const int ct = bid & 7;
  const int pt = (bid >> 3) & 3;
  const int b = bid >> 5;
  const int p0 = pt * 49, c0 = ct * 64;
  const int tbase = b * 196 + p0;
  for (int idx = threadIdx.x; idx < 3136; idx += 256) {
    const int pl = idx >> 6;
    const int cl = idx & 63;
    tile[pl][cl] = F[(long)(tbase + pl) * 512 + c0 + cl];
  }
  __syncthreads();
  const long obase = (long)b * 100352;
  for (int idx = threadIdx.x; idx < 3136; idx += 256) {
    const int cl = idx / 49;
    const int pl = idx - cl * 49;
    out[obase + (long)(c0 + cl) * 196 + p0 + pl] = tile[pl][cl];
  }
}

extern "C" void kernel_launch(void* const* d_in, const int* in_sizes, int n_in,
                              void* d_out, int out_size, void* d_ws, size_t ws_size,
                              hipStream_t stream) {
  const float* x      = (const float*)d_in[0];
  const float* ln1_w  = (const float*)d_in[1];
  const float* ln1_b  = (const float*)d_in[2];
  const float* qkv_w  = (const float*)d_in[3];
  const float* qkv_b  = (const float*)d_in[4];
  const float* relb   = (const float*)d_in[5];
  const float* proj_w = (const float*)d_in[6];
  const float* proj_b = (const float*)d_in[7];
  const float* gamma1 = (const float*)d_in[8];
  const float* ln2_w  = (const float*)d_in[9];
  const float* ln2_b  = (const float*)d_in[10];
  const float* fc1_w  = (const float*)d_in[11];
  const float* fc1_b  = (const float*)d_in[12];
  const float* fc2_w  = (const float*)d_in[13];
  const float* fc2_b  = (const float*)d_in[14];
  const float* gamma2 = (const float*)d_in[15];
  float* out = (float*)d_out;
  char* ws = (char*)d_ws;

  float*   mu1 = (float*)(ws + 0);
  float*   rs1 = (float*)(ws + 100352);
  float*   mu2 = (float*)(ws + 200704);
  float*   rs2 = (float*)(ws + 301056);
  uint8_t* Wq  = (uint8_t*)(ws + 401408);    //   786,432 B
  uint8_t* Wp  = (uint8_t*)(ws + 1187840);   //   262,144 B
  uint8_t* W1  = (uint8_t*)(ws + 1449984);   // 1,048,576 B
  uint8_t* W2  = (uint8_t*)(ws + 2498560);   // 1,048,576 B
  float*   BMt = (float*)  (ws + 3547136);   // 1,048,576 B bias+mask table
  uint8_t* Afp = (uint8_t*)(ws + 4595712);   // 12,845,056 B
  float*   XT  = (float*)  (ws + 17440768);  // 51,380,224 B raw x token-major
  float*   X1  = (float*)  (ws + 68820992);  // 51,380,224 B
  uint8_t* QKV = (uint8_t*)(ws + 120201216); // 38,535,168 B
  uint8_t* AT  = (uint8_t*)(ws + 158736384); // 12,845,056 B
  uint8_t* Hb  = (uint8_t*)(ws + 120201216); // 51,380,224 B overlaps dead QKV+AT exactly

  // weights -> fp8, BM table
  cvt_fp8<<<768,  256, 0, stream>>>(qkv_w, Wq, 196608);
  cvt_fp8<<<256,  256, 0, stream>>>(proj_w, Wp, 65536);
  cvt_fp8<<<1024, 256, 0, stream>>>(fc1_w, W1, 262144);
  cvt_fp8<<<1024, 256, 0, stream>>>(fc2_w, W2, 262144);
  bm_build<<<64, 256, 0, stream>>>(relb, BMt);

  // LN1 + transpose to token-major
  ln_stats_nchw<<<392, 256, 0, stream>>>(x, mu1, rs1);
  ln1_apply<<<4096, 256, 0, stream>>>(x, mu1, rs1, ln1_w, ln1_b, XT, Afp);

  // qkv GEMM (q pre-scaled)
  gemm_fp8<0><<<dim3(196, 12), 256, 0, stream>>>(Afp, Wq, qkv_b, nullptr, nullptr, QKV, nullptr, 512, 1536);

  // shifted-window attention (MFMA)
  attn_mfma<<<2048, 256, 0, stream>>>(QKV, BMt, AT);

  // proj GEMM, fused X1 = x + g1*(out+b)
  gemm_fp8<1><<<dim3(196, 4), 256, 0, stream>>>(AT, Wp, proj_b, XT, gamma1, nullptr, X1, 512, 512);

  // LN2
  ln_stats_row<<<6272, 256, 0, stream>>>(X1, mu2, rs2);
  ln2_apply<<<12544, 256, 0, stream>>>(X1, mu2, rs2, ln2_w, ln2_b, Afp);

  // MLP
  gemm_fp8<2><<<dim3(196, 16), 256, 0, stream>>>(Afp, W1, fc1_b, nullptr, nullptr, Hb, nullptr, 512, 2048);
  gemm_fp8<3><<<dim3(196, 4), 256, 0, stream>>>(Hb, W2, fc2_b, X1, gamma2, nullptr, X1, 2048, 512);

  // token-major -> NCHW
  out_transpose<<<4096, 256, 0, stream>>>(X1, out);
}

// Round 5
// 478.626 us; speedup vs baseline: 1.3419x; 1.0354x over previous
//
#include <hip/hip_runtime.h>
#include <cmath>
#include <cstdint>

typedef float floatx4 __attribute__((ext_vector_type(4)));
typedef float floatx2 __attribute__((ext_vector_type(2)));

#define EPS_ 1e-5f
#define QSCALE 0.17677669529663689f
#define NWIN 49

// ---------- async global->LDS (16B per lane) ----------
__device__ __forceinline__ void gload16(const uint8_t* g, uint8_t* l) {
  __builtin_amdgcn_global_load_lds(
      (const __attribute__((address_space(1))) void*)g,
      (__attribute__((address_space(3))) void*)l, 16, 0, 0);
}

// ---------- fp8 e4m3 pack/unpack (word-select must be an immediate) ----------
template<bool HI>
__device__ __forceinline__ int pk_fp8(float a, float b, int old) {
  return __builtin_amdgcn_cvt_pk_fp8_f32(a, b, old, HI);
}
__device__ __forceinline__ int pk_fp8x4(float v0, float v1, float v2, float v3) {
  int w = pk_fp8<false>(v0, v1, 0);
  return pk_fp8<true>(v2, v3, w);
}

// ---------- fp32 -> fp8 weight conversion, all 4 weights in one launch ----------
__global__ void cvt_all(const float* __restrict__ qkv_w, const float* __restrict__ proj_w,
                        const float* __restrict__ fc1_w, const float* __restrict__ fc2_w,
                        uint8_t* __restrict__ Wq, uint8_t* __restrict__ Wp,
                        uint8_t* __restrict__ W1, uint8_t* __restrict__ W2) {
  const int bid = blockIdx.x;
  const float* s; uint8_t* d; int i;
  if (bid < 768)       { s = qkv_w;  d = Wq; i = bid * 256 + threadIdx.x; }
  else if (bid < 1024) { s = proj_w; d = Wp; i = (bid - 768) * 256 + threadIdx.x; }
  else if (bid < 2048) { s = fc1_w;  d = W1; i = (bid - 1024) * 256 + threadIdx.x; }
  else                 { s = fc2_w;  d = W2; i = (bid - 2048) * 256 + threadIdx.x; }
  float4 v = ((const float4*)s)[i];
  ((int*)d)[i] = pk_fp8x4(v.x, v.y, v.z, v.w);
}

// ---------- LN1 stats over C for NCHW input ----------
__global__ __launch_bounds__(256)
void ln_stats_nchw(const float* __restrict__ x, float* __restrict__ mu, float* __restrict__ rs) {
  const int tl = threadIdx.x & 63;
  const int wv = threadIdx.x >> 6;
  const int t = blockIdx.x * 64 + tl;       // token = b*196 + p
  const int b = t / 196;
  const int p = t - b * 196;
  const float* xp = x + (long)b * 100352 + p;
  float s = 0.f, ss = 0.f;
  const int cbeg = wv * 128;
  for (int c = cbeg; c < cbeg + 128; ++c) {
    const float v = xp[(long)c * 196];
    s += v; ss += v * v;
  }
  __shared__ float sb[4][64], qb[4][64];
  sb[wv][tl] = s; qb[wv][tl] = ss;
  __syncthreads();
  if (wv == 0) {
    s  = sb[0][tl] + sb[1][tl] + sb[2][tl] + sb[3][tl];
    ss = qb[0][tl] + qb[1][tl] + qb[2][tl] + qb[3][tl];
    const float m = s * (1.f / 512.f);
    const float var = ss * (1.f / 512.f) - m * m;
    mu[t] = m;
    rs[t] = rsqrtf(var + EPS_);
  }
}

// ---------- LN1 apply + NCHW->token-major transpose; writes XT (raw x, f32) and A (normalized, fp8) ----------
__global__ __launch_bounds__(256)
void ln1_apply(const float* __restrict__ x, const float* __restrict__ mu, const float* __restrict__ rs,
               const float* __restrict__ w, const float* __restrict__ bb,
               float* __restrict__ XT, uint8_t* __restrict__ A) {
  __shared__ float tile[64][53];            // 53: gcd(53,32)=1 -> conflict-free
  const int bid = blockIdx.x;
  const int ct = bid & 7;
  const int pt = (bid >> 3) & 3;
  const int b = bid >> 5;
  const int p0 = pt * 49, c0 = ct * 64;
  const long xbase = (long)b * 100352;
  for (int idx = threadIdx.x; idx < 3136; idx += 256) {
    const int cl = idx / 49;
    const int pl = idx - cl * 49;
    tile[cl][pl] = x[xbase + (long)(c0 + cl) * 196 + p0 + pl];
  }
  __syncthreads();
  const int tbase = b * 196 + p0;
  for (int idx = threadIdx.x; idx < 3136; idx += 256) {
    const int pl = idx >> 6;
    const int cl = idx & 63;
    const int t = tbase + pl;
    XT[(long)t * 512 + c0 + cl] = tile[cl][pl];
  }
  for (int idx = threadIdx.x; idx < 784; idx += 256) {
    const int pl = idx >> 4;                // 0..48
    const int cq = (idx & 15) << 2;         // 0..60 step 4
    const int t = tbase + pl;
    const float m = mu[t], rr = rs[t];
    float v0 = (tile[cq + 0][pl] - m) * rr * w[c0 + cq + 0] + bb[c0 + cq + 0];
    float v1 = (tile[cq + 1][pl] - m) * rr * w[c0 + cq + 1] + bb[c0 + cq + 1];
    float v2 = (tile[cq + 2][pl] - m) * rr * w[c0 + cq + 2] + bb[c0 + cq + 2];
    float v3 = (tile[cq + 3][pl] - m) * rr * w[c0 + cq + 3] + bb[c0 + cq + 3];
    *(int*)(A + (long)t * 512 + c0 + cq) = pk_fp8x4(v0, v1, v2, v3);
  }
}

// ---------- LN2 apply from raw sums -> fp8 tokens ----------
__global__ __launch_bounds__(256)
void ln2_apply(const float* __restrict__ X, const float* __restrict__ S1,
               const float* __restrict__ S2, const float* __restrict__ w,
               const float* __restrict__ bb, uint8_t* __restrict__ Z) {
  const long i = ((long)blockIdx.x * 256 + threadIdx.x) * 4;
  const int t = (int)(i >> 9);
  const int c = (int)(i & 511);
  const float m = S1[t] * (1.f / 512.f);
  const float var = S2[t] * (1.f / 512.f) - m * m;
  const float r = rsqrtf(var + EPS_);
  const float4 v = *(const float4*)(X + i);
  float v0 = (v.x - m) * r * w[c + 0] + bb[c + 0];
  float v1 = (v.y - m) * r * w[c + 1] + bb[c + 1];
  float v2 = (v.z - m) * r * w[c + 2] + bb[c + 2];
  float v3 = (v.w - m) * r * w[c + 3] + bb[c + 3];
  *(int*)(Z + i) = pk_fp8x4(v0, v1, v2, v3);
}

// ---------- fp8 MFMA GEMM, 128x128 tile, BK=64 (EPI 0: qkv, EPI 2: fc1) ----------
template<int EPI>
__global__ __launch_bounds__(256)
void gemm_fp8(const uint8_t* __restrict__ A, const uint8_t* __restrict__ Bw,
              const float* __restrict__ bias, uint8_t* __restrict__ outb,
              const int K, const int N) {
  __shared__ uint8_t As[8192];
  __shared__ uint8_t Bs[8192];
  const int tid = threadIdx.x;
  const int wave = tid >> 6, lane = tid & 63;
  const int lm = lane & 15, lq = lane >> 4;
  const long m0 = (long)blockIdx.x * 128;
  const long n0 = (long)blockIdx.y * 128;
  const int srow = tid >> 1;
  const int half16 = (tid & 1) << 4;
  const uint8_t* ag = A + (m0 + srow) * K + half16;
  const int wrow = (srow & ~63) + (srow & 15) * 4 + ((srow >> 4) & 3);
  const uint8_t* bg = Bw + (n0 + wrow) * K + half16;
  uint8_t* lA0 = As + tid * 16;
  uint8_t* lA1 = As + 4096 + tid * 16;
  uint8_t* lB0 = Bs + tid * 16;
  uint8_t* lB1 = Bs + 4096 + tid * 16;
  const int wm = (wave >> 1) << 6;
  const int wn = (wave & 1) << 6;
  floatx4 acc[4][4] = {};
  const int nk = K >> 6;
  for (int kt = 0; kt < nk; ++kt) {
    gload16(ag, lA0);
    gload16(ag + 32, lA1);
    gload16(bg, lB0);
    gload16(bg + 32, lB1);
    __syncthreads();
    #pragma unroll
    for (int ks = 0; ks < 2; ++ks) {
      long af[4], bfv[4];
      #pragma unroll
      for (int i = 0; i < 4; ++i)
        af[i] = *(const long*)(As + ks * 4096 + (wm + i * 16 + lm) * 32 + lq * 8);
      #pragma unroll
      for (int j = 0; j < 4; ++j)
        bfv[j] = *(const long*)(Bs + ks * 4096 + (wn + j * 16 + lm) * 32 + lq * 8);
      #pragma unroll
      for (int i = 0; i < 4; ++i)
        #pragma unroll
        for (int j = 0; j < 4; ++j)
          acc[i][j] = __builtin_amdgcn_mfma_f32_16x16x32_fp8_fp8(af[i], bfv[j], acc[i][j], 0, 0, 0);
    }
    __syncthreads();
    ag += 64; bg += 64;
  }
  const int cb = (int)n0 + wn + lm * 4;
  const float4 b4 = *(const float4*)(bias + cb);
  const float qs = (EPI == 0 && cb < 512) ? QSCALE : 1.f;
  #pragma unroll
  for (int i = 0; i < 4; ++i) {
    #pragma unroll
    for (int r = 0; r < 4; ++r) {
      const long rowg = m0 + wm + i * 16 + lq * 4 + r;
      float v0 = acc[i][0][r] + b4.x;
      float v1 = acc[i][1][r] + b4.y;
      float v2 = acc[i][2][r] + b4.z;
      float v3 = acc[i][3][r] + b4.w;
      if (EPI == 0) {
        *(int*)(outb + rowg * (long)N + cb) = pk_fp8x4(v0 * qs, v1 * qs, v2 * qs, v3 * qs);
      } else {
        v0 = 0.5f * v0 * (1.f + erff(v0 * 0.70710678118654752f));
        v1 = 0.5f * v1 * (1.f + erff(v1 * 0.70710678118654752f));
        v2 = 0.5f * v2 * (1.f + erff(v2 * 0.70710678118654752f));
        v3 = 0.5f * v3 * (1.f + erff(v3 * 0.70710678118654752f));
        *(int*)(outb + rowg * (long)N + cb) = pk_fp8x4(v0, v1, v2, v3);
      }
    }
  }
}

// ---------- fp8 MFMA GEMM, 64x128 tile, BK=64, residual epilogue (proj / fc2) ----------
// out = res + gamma*(acc+bias); STATS: fused LN-stat raw sums via 16-lane shfl + atomics
template<bool STATS>
__global__ __launch_bounds__(256)
void gemm64_fp8(const uint8_t* __restrict__ A, const uint8_t* __restrict__ Bw,
                const float* __restrict__ bias, const float* __restrict__ res,
                const float* __restrict__ gamma, float* __restrict__ outf,
                float* __restrict__ S1, float* __restrict__ S2,
                const int K, const int N) {
  __shared__ uint8_t As[4096];
  __shared__ uint8_t Bs[8192];
  const int tid = threadIdx.x;
  const int wave = tid >> 6, lane = tid & 63;
  const int lm = lane & 15, lq = lane >> 4;
  const long m0 = (long)blockIdx.x * 64;
  const long n0 = (long)blockIdx.y * 128;
  // A staging: dest = As + tid*16, layout addr = ks*2048 + row*32 + h*16
  const int arow = (tid >> 1) & 63;
  const int akk = ((tid >> 7) << 5) | ((tid & 1) << 4);
  const uint8_t* ag = A + (m0 + arow) * K + akk;
  // B staging (col-permuted rows for contiguous epilogue cols)
  const int srow = tid >> 1;
  const int half16 = (tid & 1) << 4;
  const int wrow = (srow & ~63) + (srow & 15) * 4 + ((srow >> 4) & 3);
  const uint8_t* bg = Bw + (n0 + wrow) * K + half16;
  uint8_t* lA = As + tid * 16;
  uint8_t* lB0 = Bs + tid * 16;
  uint8_t* lB1 = Bs + 4096 + tid * 16;
  const int wm = (wave >> 1) << 5;   // {0,32}
  const int wn = (wave & 1) << 6;    // {0,64}
  floatx4 acc[2][4] = {};
  const int nk = K >> 6;
  for (int kt = 0; kt < nk; ++kt) {
    gload16(ag, lA);
    gload16(bg, lB0);
    gload16(bg + 32, lB1);
    __syncthreads();
    #pragma unroll
    for (int ks = 0; ks < 2; ++ks) {
      long af[2], bfv[4];
      #pragma unroll
      for (int i = 0; i < 2; ++i)
        af[i] = *(const long*)(As + ks * 2048 + (wm + i * 16 + lm) * 32 + lq * 8);
      #pragma unroll
      for (int j = 0; j < 4; ++j)
        bfv[j] = *(const long*)(Bs + ks * 4096 + (wn + j * 16 + lm) * 32 + lq * 8);
      #pragma unroll
      for (int i = 0; i < 2; ++i)
        #pragma unroll
        for (int j = 0; j < 4; ++j)
          acc[i][j] = __builtin_amdgcn_mfma_f32_16x16x32_fp8_fp8(af[i], bfv[j], acc[i][j], 0, 0, 0);
    }
    __syncthreads();
    ag += 64; bg += 64;
  }
  const int cb = (int)n0 + wn + lm * 4;
  const float4 b4 = *(const float4*)(bias + cb);
  const float4 g4 = *(const float4*)(gamma + cb);
  #pragma unroll
  for (int i = 0; i < 2; ++i) {
    #pragma unroll
    for (int r = 0; r < 4; ++r) {
      const long rowg = m0 + wm + i * 16 + lq * 4 + r;
      const long o = rowg * (long)N + cb;
      const float4 rv = *(const float4*)(res + o);
      float4 ov;
      ov.x = rv.x + g4.x * (acc[i][0][r] + b4.x);
      ov.y = rv.y + g4.y * (acc[i][1][r] + b4.y);
      ov.z = rv.z + g4.z * (acc[i][2][r] + b4.z);
      ov.w = rv.w + g4.w * (acc[i][3][r] + b4.w);
      *(float4*)(outf + o) = ov;
      if (STATS) {
        float s = ov.x + ov.y + ov.z + ov.w;
        float ss = ov.x * ov.x + ov.y * ov.y + ov.z * ov.z + ov.w * ov.w;
        s += __shfl_xor(s, 1);  ss += __shfl_xor(ss, 1);
        s += __shfl_xor(s, 2);  ss += __shfl_xor(ss, 2);
        s += __shfl_xor(s, 4);  ss += __shfl_xor(ss, 4);
        s += __shfl_xor(s, 8);  ss += __shfl_xor(ss, 8);
        if (lm == 0) {
          atomicAdd(S1 + rowg, s);
          atomicAdd(S2 + rowg, ss);
        }
      }
    }
  }
}

// ---------- BM table: bias+mask+padding in MFMA C-layout order ----------
__global__ __launch_bounds__(256)
void bm_build(const float* __restrict__ rel_bias, float* __restrict__ BM) {
  const int hw = blockIdx.x;           // head*4 + wpos
  const int head = hw >> 2, wpos = hw & 3;
  const int wi = wpos >> 1, wj = wpos & 1;
  for (int k = 0; k < 4; ++k) {
    const int idx = k * 256 + threadIdx.x;   // tile*64 + lane
    const int tile = idx >> 6, l = idx & 63;
    const int qi = tile >> 2, ti = tile & 3;
    const int n = l & 15, g = l >> 4;
    const int query = qi * 16 + n;
    const int qy = query / 7, qx = query - qy * 7;
    const int hh = wi * 7 + qy, ww = wj * 7 + qx;
    const int ri = (hh < 7 ? 0 : (hh < 11 ? 1 : 2)) * 3 + (ww < 7 ? 0 : (ww < 11 ? 1 : 2));
    float4 ov;
    float vv[4];
    #pragma unroll
    for (int r = 0; r < 4; ++r) {
      const int key = ti * 16 + g * 4 + r;
      float v;
      if (query >= 49 || key >= 49) {
        v = -3.0e38f;
      } else {
        const int ky = key / 7, kx = key - ky * 7;
        const int bidx = (qy - ky + 6) * 13 + (qx - kx + 6);
        const int h2 = wi * 7 + ky, w2 = wj * 7 + kx;
        const int rj = (h2 < 7 ? 0 : (h2 < 11 ? 1 : 2)) * 3 + (w2 < 7 ? 0 : (w2 < 11 ? 1 : 2));
        v = rel_bias[bidx * 16 + head] + ((ri != rj) ? -100.f : 0.f);
      }
      vv[r] = v;
    }
    ov.x = vv[0]; ov.y = vv[1]; ov.z = vv[2]; ov.w = vv[3];
    *(float4*)(BM + ((long)(hw * 16 + tile) << 8) + l * 4) = ov;
  }
}

// ---------- 4x4 byte transpose ----------
__device__ __forceinline__ void tr4(const uint32_t d[4], uint32_t o[4]) {
  #pragma unroll
  for (int c = 0; c < 4; ++c)
    o[c] = ((d[0] >> (8 * c)) & 0xffu) | (((d[1] >> (8 * c)) & 0xffu) << 8)
         | (((d[2] >> (8 * c)) & 0xffu) << 16) | (((d[3] >> (8 * c)) & 0xffu) << 24);
}

// ---------- MFMA windowed attention: one wave per (window, head) ----------
__global__ __launch_bounds__(256)
void attn_mfma(const uint8_t* __restrict__ QKV, const float* __restrict__ BM,
               uint8_t* __restrict__ AT) {
  __shared__ uint8_t lds[4][9984];   // per-wave: Pb 64x72, Vt 32x72, Ot 64x48
  const int wave = threadIdx.x >> 6, lane = threadIdx.x & 63;
  const int n = lane & 15, g = lane >> 4;
  const int gw = blockIdx.x * 4 + wave;
  const int wd = gw >> 4, head = gw & 15;
  const int b = wd >> 2, wpos = wd & 3;
  const int wi = wpos >> 1, wj = wpos & 1;
  uint8_t* Pb = lds[wave];
  uint8_t* Vt = lds[wave] + 4608;
  uint8_t* Ot = lds[wave] + 6912;
  const long base = (long)b * 196 * 1536;
  auto tok = [&](int slot) -> int {
    const int ty = slot / 7, tx = slot - ty * 7;
    int h = wi * 7 + ty + 3; if (h >= 14) h -= 14;
    int w = wj * 7 + tx + 3; if (w >= 14) w -= 14;
    return h * 14 + w;
  };
  long Ak[4], Bq[4];
  #pragma unroll
  for (int t4 = 0; t4 < 4; ++t4) {
    int slot = t4 * 16 + n; if (slot > 48) slot = 48;
    const long tb = base + (long)tok(slot) * 1536 + head * 32 + g * 8;
    Bq[t4] = *(const long*)(QKV + tb);          // Q rows (B operand)
    Ak[t4] = *(const long*)(QKV + tb + 512);    // K rows (A operand)
  }
  #pragma unroll
  for (int bb2 = 0; bb2 < 2; ++bb2) {
    const int blk = lane + bb2 * 64;
    const int dq = blk >> 4, tq = blk & 15;
    uint32_t d4[4], o4[4];
    #pragma unroll
    for (int r = 0; r < 4; ++r) {
      int slot = tq * 4 + r; if (slot > 48) slot = 48;
      d4[r] = *(const uint32_t*)(QKV + base + (long)tok(slot) * 1536 + 1024 + head * 32 + dq * 4);
    }
    tr4(d4, o4);
    #pragma unroll
    for (int c = 0; c < 4; ++c)
      *(uint32_t*)(Vt + (dq * 4 + c) * 72 + tq * 4) = o4[c];
  }
  floatx4 acc[4][4];
  const float* bmw = BM + ((long)(head * 4 + wpos) << 12) + lane * 4;
  #pragma unroll
  for (int qi = 0; qi < 4; ++qi)
    #pragma unroll
    for (int ti = 0; ti < 4; ++ti) {
      const float4 bv = *(const float4*)(bmw + ((qi * 4 + ti) << 8));
      acc[qi][ti][0] = bv.x; acc[qi][ti][1] = bv.y;
      acc[qi][ti][2] = bv.z; acc[qi][ti][3] = bv.w;
    }
  #pragma unroll
  for (int qi = 0; qi < 4; ++qi)
    #pragma unroll
    for (int ti = 0; ti < 4; ++ti)
      acc[qi][ti] = __builtin_amdgcn_mfma_f32_16x16x32_fp8_fp8(Ak[ti], Bq[qi], acc[qi][ti], 0, 0, 0);
  #pragma unroll
  for (int qi = 0; qi < 4; ++qi) {
    float mx = -3.0e38f;
    #pragma unroll
    for (int ti = 0; ti < 4; ++ti)
      #pragma unroll
      for (int r = 0; r < 4; ++r) mx = fmaxf(mx, acc[qi][ti][r]);
    mx = fmaxf(mx, __shfl_xor(mx, 16));
    mx = fmaxf(mx, __shfl_xor(mx, 32));
    float sum = 0.f;
    #pragma unroll
    for (int ti = 0; ti < 4; ++ti)
      #pragma unroll
      for (int r = 0; r < 4; ++r) {
        const float e = __expf(acc[qi][ti][r] - mx);
        acc[qi][ti][r] = e; sum += e;
      }
    sum += __shfl_xor(sum, 16);
    sum += __shfl_xor(sum, 32);
    const float inv = 1.f / sum;
    #pragma unroll
    for (int ti = 0; ti < 4; ++ti) {
      const int pw = pk_fp8x4(acc[qi][ti][0] * inv, acc[qi][ti][1] * inv,
                              acc[qi][ti][2] * inv, acc[qi][ti][3] * inv);
      *(uint32_t*)(Pb + (qi * 16 + n) * 72 + ti * 16 + g * 4) = pw;
    }
  }
  asm volatile("s_waitcnt lgkmcnt(0)" ::: "memory");
  long Bv[2][2];
  #pragma unroll
  for (int ni = 0; ni < 2; ++ni)
    #pragma unroll
    for (int s = 0; s < 2; ++s)
      Bv[ni][s] = *(const long*)(Vt + (ni * 16 + n) * 72 + s * 32 + g * 8);
  floatx4 o[4][2] = {};
  #pragma unroll
  for (int qi = 0; qi < 4; ++qi)
    #pragma unroll
    for (int s = 0; s < 2; ++s) {
      const long Ap = *(const long*)(Pb + (qi * 16 + n) * 72 + s * 32 + g * 8);
      #pragma unroll
      for (int ni = 0; ni < 2; ++ni)
        o[qi][ni] = __builtin_amdgcn_mfma_f32_16x16x32_fp8_fp8(Ap, Bv[ni][s], o[qi][ni], 0, 0, 0);
    }
  #pragma unroll
  for (int qi = 0; qi < 4; ++qi)
    #pragma unroll
    for (int ni = 0; ni < 2; ++ni)
      #pragma unroll
      for (int r = 0; r < 4; ++r)
        Ot[(qi * 16 + g * 4 + r) * 48 + ni * 16 + n] =
            (uint8_t)(pk_fp8<false>(o[qi][ni][r], 0.f, 0) & 0xff);
  asm volatile("s_waitcnt lgkmcnt(0)" ::: "memory");
  if (lane < 49) {
    const int t = tok(lane);
    uint8_t* op = AT + ((long)b * 196 + t) * 512 + head * 32;
    const int4 w0 = *(const int4*)(Ot + lane * 48);
    const int4 w1 = *(const int4*)(Ot + lane * 48 + 16);
    *(int4*)op = w0;
    *(int4*)(op + 16) = w1;
  }
}

// ---------- final token-major f32 -> NCHW ----------
__global__ __launch_bounds__(256)
void out_transpose(const float* __restrict__ F, float* __restrict__ out) {
  __shared__ float tile[49][65];
  const int bid = blockIdx.x;
  const int ct = bid & 7;
  const int pt = (bid >> 3) & 3;
  const int b = bid >> 5;
  const int p0 = pt * 49, c0 = ct * 64;
  const int tbase = b * 196 + p0;
  for (int idx = threadIdx.x; idx < 3136; idx += 256) {
    const int pl = idx >> 6;
    const int cl = idx & 63;
    tile[pl][cl] = F[(long)(tbase + pl) * 512 + c0 + cl];
  }
  __syncthreads();
  const long obase = (long)b * 100352;
  for (int idx = threadIdx.x; idx < 3136; idx += 256) {
    const int cl = idx / 49;
    const int pl = idx - cl * 49;
    out[obase + (long)(c0 + cl) * 196 + p0 + pl] = tile[pl][cl];
  }
}

extern "C" void kernel_launch(void* const* d_in, const int* in_sizes, int n_in,
                              void* d_out, int out_size, void* d_ws, size_t ws_size,
                              hipStream_t stream) {
  const float* x      = (const float*)d_in[0];
  const float* ln1_w  = (const float*)d_in[1];
  const float* ln1_b  = (const float*)d_in[2];
  const float* qkv_w  = (const float*)d_in[3];
  const float* qkv_b  = (const float*)d_in[4];
  const float* relb   = (const float*)d_in[5];
  const float* proj_w = (const float*)d_in[6];
  const float* proj_b = (const float*)d_in[7];
  const float* gamma1 = (const float*)d_in[8];
  const float* ln2_w  = (const float*)d_in[9];
  const float* ln2_b  = (const float*)d_in[10];
  const float* fc1_w  = (const float*)d_in[11];
  const float* fc1_b  = (const float*)d_in[12];
  const float* fc2_w  = (const float*)d_in[13];
  const float* fc2_b  = (const float*)d_in[14];
  const float* gamma2 = (const float*)d_in[15];
  float* out = (float*)d_out;
  char* ws = (char*)d_ws;

  float*   mu1 = (float*)(ws + 0);
  float*   rs1 = (float*)(ws + 100352);
  float*   S1  = (float*)(ws + 200704);      // LN2 raw sum
  float*   S2  = (float*)(ws + 301056);      // LN2 raw sumsq
  uint8_t* Wq  = (uint8_t*)(ws + 401408);    //   786,432 B
  uint8_t* Wp  = (uint8_t*)(ws + 1187840);   //   262,144 B
  uint8_t* W1  = (uint8_t*)(ws + 1449984);   // 1,048,576 B
  uint8_t* W2  = (uint8_t*)(ws + 2498560);   // 1,048,576 B
  float*   BMt = (float*)  (ws + 3547136);   // 1,048,576 B bias+mask table
  uint8_t* Afp = (uint8_t*)(ws + 4595712);   // 12,845,056 B
  float*   XT  = (float*)  (ws + 17440768);  // 51,380,224 B raw x token-major
  float*   X1  = (float*)  (ws + 68820992);  // 51,380,224 B
  uint8_t* QKV = (uint8_t*)(ws + 120201216); // 38,535,168 B
  uint8_t* AT  = (uint8_t*)(ws + 158736384); // 12,845,056 B
  uint8_t* Hb  = (uint8_t*)(ws + 120201216); // 51,380,224 B overlaps dead QKV+AT exactly

  // zero LN2 sum buffers (atomics accumulate into them during proj)
  hipMemsetAsync(ws + 200704, 0, 200704, stream);

  // weights -> fp8 (single launch), BM table
  cvt_all<<<3072, 256, 0, stream>>>(qkv_w, proj_w, fc1_w, fc2_w, Wq, Wp, W1, W2);
  bm_build<<<64, 256, 0, stream>>>(relb, BMt);

  // LN1 + transpose to token-major
  ln_stats_nchw<<<392, 256, 0, stream>>>(x, mu1, rs1);
  ln1_apply<<<4096, 256, 0, stream>>>(x, mu1, rs1, ln1_w, ln1_b, XT, Afp);

  // qkv GEMM (q pre-scaled)
  gemm_fp8<0><<<dim3(196, 12), 256, 0, stream>>>(Afp, Wq, qkv_b, QKV, 512, 1536);

  // shifted-window attention (MFMA)
  attn_mfma<<<2048, 256, 0, stream>>>(QKV, BMt, AT);

  // proj GEMM (64x128 tile), fused X1 = x + g1*(out+b) + LN2 stats
  gemm64_fp8<true><<<dim3(392, 4), 256, 0, stream>>>(AT, Wp, proj_b, XT, gamma1, X1, S1, S2, 512, 512);

  // LN2 apply from raw sums
  ln2_apply<<<12544, 256, 0, stream>>>(X1, S1, S2, ln2_w, ln2_b, Afp);

  // MLP
  gemm_fp8<2><<<dim3(196, 16), 256, 0, stream>>>(Afp, W1, fc1_b, Hb, 512, 2048);
  gemm64_fp8<false><<<dim3(392, 4), 256, 0, stream>>>(Hb, W2, fc2_b, X1, gamma2, X1, nullptr, nullptr, 2048, 512);

  // token-major -> NCHW
  out_transpose<<<4096, 256, 0, stream>>>(X1, out);
}